// Round 1
// baseline (231.491 us; speedup 1.0000x reference)
//
#include <hip/hip_runtime.h>
#include <math.h>

// Problem shape (fixed by the reference): x = (B=4, S=8192, D=1024) float32.
// out[b,s,d] = x[b,s,d] + pos[s,d]
//   pos[s,d] = sin(s / 10000^((d+1)/D)) if d even, cos(...) if d odd.
#define PE_S 8192
#define PE_D 1024
#define PE_B 4

// One thread per (s, d-quad). Computes the 4 pos values ONCE, then loops over
// the 4 batch planes doing float4 load/add/store. Fully coalesced: consecutive
// threads touch consecutive 16B segments within a plane.
__global__ __launch_bounds__(256) void position_encoder_kernel(
    const float* __restrict__ x, float* __restrict__ out) {
    const int tid = blockIdx.x * blockDim.x + threadIdx.x;  // 0 .. S*D/4-1
    const int d4  = tid & (PE_D / 4 - 1);                   // 0..255
    const int s   = tid >> 8;                               // 0..8191 (log2(D/4)=8)
    const int d0  = d4 << 2;                                // aligned quad start

    const float fs = (float)s;
    // pf_j = s * 10000^(-(j+1)/D) = s * 2^((j+1) * a2),  a2 = -log2(10000)/1024
    const float a2 = -0.012976281620653760f;
    const float w0 = exp2f((float)(d0 + 1) * a2);
    const float w1 = exp2f((float)(d0 + 2) * a2);
    const float w2 = exp2f((float)(d0 + 3) * a2);
    const float w3 = exp2f((float)(d0 + 4) * a2);

    // d0 is even -> sin, d0+1 odd -> cos, d0+2 even -> sin, d0+3 odd -> cos.
    // Use libm sinf/cosf (ocml): pf reaches ~8191 rad, needs real range reduction.
    float4 p;
    p.x = sinf(fs * w0);
    p.y = cosf(fs * w1);
    p.z = sinf(fs * w2);
    p.w = cosf(fs * w3);

    const size_t base  = (size_t)s * PE_D + (size_t)d0;
    const size_t plane = (size_t)PE_S * PE_D;
#pragma unroll
    for (int b = 0; b < PE_B; ++b) {
        const float4 v = *reinterpret_cast<const float4*>(x + (size_t)b * plane + base);
        float4 o;
        o.x = v.x + p.x;
        o.y = v.y + p.y;
        o.z = v.z + p.z;
        o.w = v.w + p.w;
        *reinterpret_cast<float4*>(out + (size_t)b * plane + base) = o;
    }
}

extern "C" void kernel_launch(void* const* d_in, const int* in_sizes, int n_in,
                              void* d_out, int out_size, void* d_ws, size_t ws_size,
                              hipStream_t stream) {
    const float* x = (const float*)d_in[0];
    float* out = (float*)d_out;

    const int threads = 256;
    const int total_quads = PE_S * PE_D / 4;       // 2,097,152 threads
    const int blocks = total_quads / threads;      // 8192 blocks
    position_encoder_kernel<<<blocks, threads, 0, stream>>>(x, out);
}